// Round 5
// baseline (493.232 us; speedup 1.0000x reference)
//
#include <hip/hip_runtime.h>

typedef unsigned short u16;
typedef float f32x4 __attribute__((ext_vector_type(4)));
typedef short s16x8 __attribute__((ext_vector_type(8)));
typedef unsigned short u16x4 __attribute__((ext_vector_type(4)));

#define EPS 1e-6f

static __device__ __forceinline__ u16 f2bf(float f) {
  unsigned u = __float_as_uint(f);
  u += 0x7fffu + ((u >> 16) & 1u);   // RNE
  return (u16)(u >> 16);
}
static __device__ __forceinline__ float bf2f(u16 h) {
  return __uint_as_float(((unsigned)h) << 16);
}

// ---------------- Stage 1: transpose weights to bf16 [col][k] (unswizzled) ----------------
__global__ void wtrans_kernel(const float* __restrict__ Wq, const float* __restrict__ Wk,
                              const float* __restrict__ Wv,
                              u16* __restrict__ WqT, u16* __restrict__ WkT, u16* __restrict__ WvT) {
  int b = blockIdx.x;
  int mat = b >> 4, cg = b & 15;
  const float* W = mat == 0 ? Wq : (mat == 1 ? Wk : Wv);
  u16* WT = mat == 0 ? WqT : (mat == 1 ? WkT : WvT);
  int t = threadIdx.x;
  int c = cg * 16 + (t & 15);
  int k0 = (t >> 4) * 16;
  for (int i = 0; i < 16; ++i) {
    int k = k0 + i;
    WT[c * 256 + k] = f2bf(W[k * 256 + c]);
  }
}

// ---------------- Stage 2: Q,K,V GEMMs ----------------
// 128-row tile, 512 thr (8 waves = 2 rowg x 4 colg of 64x32), 74KB LDS ->
// 2 blocks/CU = 16 waves/CU (the occupancy experiment). R0-proven traffic
// structure (coalesced 8KB chunk staging, FETCH ~55MB), 2 barriers/chunk,
// depth-2 register prefetch. Swapped-operand Q phase for vectorized Q stores.
__global__ __launch_bounds__(512, 4)
void qkv_kernel(const float* __restrict__ x,
                const u16* __restrict__ WqT, const u16* __restrict__ WkT, const u16* __restrict__ WvT,
                const float* __restrict__ bq, const float* __restrict__ bk, const float* __restrict__ bv,
                u16* __restrict__ Qb, u16* __restrict__ Kt, u16* __restrict__ Vt,
                float* __restrict__ ksum, int N, int NPAD) {
  __shared__ u16 xs[128 * 256];   // swizzled: idx = row*256 + (col ^ ((row&7)<<3))  (64 KB)
  __shared__ u16 wst[128 * 40];   // weight chunk [col][32k + 8 pad]                 (10 KB)
  const int tid = threadIdx.x;
  const int n0 = blockIdx.x * 128;

  // stage x tile (fp32 -> bf16), swizzled LDS writes; wave-uniform row
#pragma unroll
  for (int i = 0; i < 16; ++i) {
    int l = tid + i * 512;
    int row = l >> 6;
    int c4 = (l & 63) << 2;
    int n = n0 + row;
    float4 v = make_float4(0.f, 0.f, 0.f, 0.f);
    if (n < N) v = *(const float4*)(x + (size_t)n * 256 + c4);
    u16x4 pk;
    pk[0] = f2bf(v.x); pk[1] = f2bf(v.y); pk[2] = f2bf(v.z); pk[3] = f2bf(v.w);
    *(u16x4*)&xs[row * 256 + (c4 ^ ((row & 7) << 3))] = pk;
  }

  const int lane = tid & 63, wave = tid >> 6;
  const int quad = lane >> 4, l16 = lane & 15;
  const int wr = (wave & 1) * 64;     // row group (64 rows)
  const int clb = (wave >> 1) * 32;   // local col base within staged 128 cols

  // chunk staging map: thread loads 16B: col = tid>>2, seg = (tid&3)*8
  const int scol = tid >> 2, sseg = (tid & 3) * 8;

  auto cptr = [&](int it) -> const u16* {
    int ph = it >> 3, kc = (it & 7) * 32;
    int mat = ph >> 1, colB = (ph & 1) * 128;
    const u16* WT = mat == 0 ? WqT : (mat == 1 ? WkT : WvT);
    return WT + (size_t)(colB + scol) * 256 + kc + sseg;
  };

  // depth-2 register prefetch
  s16x8 w0 = *(const s16x8*)cptr(0);
  s16x8 w1 = *(const s16x8*)cptr(1);

  f32x4 acc[4][2] = {};
  for (int it = 0; it < 48; ++it) {
    const int ph = it >> 3, kc = (it & 7) * 32;
    const int mat = ph >> 1, colBase = (ph & 1) * 128;

    __syncthreads();                       // readers of previous chunk done (covers xs at it==0)
    *(s16x8*)&wst[scol * 40 + sseg] = (it & 1) ? w1 : w0;
    __syncthreads();                       // chunk ready

    if (it + 2 < 48) {
      if (it & 1) w1 = *(const s16x8*)cptr(it + 2);
      else        w0 = *(const s16x8*)cptr(it + 2);
    }

    s16x8 a[4], b[2];
#pragma unroll
    for (int f = 0; f < 4; ++f) {
      int r = wr + f * 16 + l16;
      a[f] = *(const s16x8*)&xs[r * 256 + ((kc + quad * 8) ^ ((r & 7) << 3))];
    }
#pragma unroll
    for (int f = 0; f < 2; ++f) b[f] = *(const s16x8*)&wst[(clb + f * 16 + l16) * 40 + quad * 8];

    if (mat == 0) {
#pragma unroll
      for (int fr = 0; fr < 4; ++fr)
#pragma unroll
        for (int fc = 0; fc < 2; ++fc)
          acc[fr][fc] = __builtin_amdgcn_mfma_f32_16x16x32_bf16(b[fc], a[fr], acc[fr][fc], 0, 0, 0);
    } else {
#pragma unroll
      for (int fr = 0; fr < 4; ++fr)
#pragma unroll
        for (int fc = 0; fc < 2; ++fc)
          acc[fr][fc] = __builtin_amdgcn_mfma_f32_16x16x32_bf16(a[fr], b[fc], acc[fr][fc], 0, 0, 0);
    }

    if ((it & 7) == 7) {
      // ---- phase epilogue ----
      if (mat == 0) {
        // swapped: col = colBase+clb+fc*16+quad*4+j, row n = n0+wr+fr*16+l16
#pragma unroll
        for (int fc = 0; fc < 2; ++fc) {
          int colg4 = colBase + clb + fc * 16 + quad * 4;
          float4 bb = *(const float4*)(bq + colg4);
#pragma unroll
          for (int fr = 0; fr < 4; ++fr) {
            int n = n0 + wr + fr * 16 + l16;
            u16x4 pk;
            pk[0] = f2bf(fmaxf(acc[fr][fc][0] + bb.x, 0.f));
            pk[1] = f2bf(fmaxf(acc[fr][fc][1] + bb.y, 0.f));
            pk[2] = f2bf(fmaxf(acc[fr][fc][2] + bb.z, 0.f));
            pk[3] = f2bf(fmaxf(acc[fr][fc][3] + bb.w, 0.f));
            if (n >= N) { pk[0] = 0; pk[1] = 0; pk[2] = 0; pk[3] = 0; }
            *(u16x4*)&Qb[(size_t)n * 256 + colg4] = pk;
          }
        }
      } else {
        u16* T = (mat == 1) ? Kt : Vt;
        const float* bias = (mat == 1) ? bk : bv;
        float ksacc[2] = {0.f, 0.f};
#pragma unroll
        for (int fc = 0; fc < 2; ++fc) {
          int colg = colBase + clb + fc * 16 + l16;
          float bb = bias[colg];
#pragma unroll
          for (int fr = 0; fr < 4; ++fr) {
            int n = n0 + wr + fr * 16 + quad * 4;
            u16x4 pk;
#pragma unroll
            for (int j = 0; j < 4; ++j) {
              float v = acc[fr][fc][j] + bb;
              if (mat == 1) v = fmaxf(v, 0.f);
              bool ok = (n + j < N);
              pk[j] = ok ? f2bf(v) : (u16)0;
              if (mat == 1) ksacc[fc] += ok ? v : 0.f;
            }
            *(u16x4*)&T[(size_t)colg * NPAD + n] = pk;
          }
        }
        if (mat == 1) {
#pragma unroll
          for (int fc = 0; fc < 2; ++fc) {
            float v = ksacc[fc];
            v += __shfl_xor(v, 16);
            v += __shfl_xor(v, 32);
            if (quad == 0) atomicAdd(&ksum[colBase + clb + fc * 16 + l16], v);
          }
        }
      }
#pragma unroll
      for (int fr = 0; fr < 4; ++fr)
#pragma unroll
        for (int fc = 0; fc < 2; ++fc) acc[fr][fc] = (f32x4){0.f, 0.f, 0.f, 0.f};
    }
  }
}

// ---------------- Stage 3: KV^T partials — barrier-free, LDS-free streaming ----------------
// Wave-owned 64x64 tiles; 64-element n-chunks = full 128B per row per visit.
__global__ __launch_bounds__(256, 3)
void kv_kernel(const u16* __restrict__ Kt, const u16* __restrict__ Vt,
               float* __restrict__ P, int NPAD, int S) {
  const int tid = threadIdx.x;
  const int s = blockIdx.x % S;
  const int g = blockIdx.x / S;
  const int ti = (g >> 1) * 128;  // e base (Vt)
  const int tj = (g & 1) * 128;   // d base (Kt)
  const int lane = tid & 63, wave = tid >> 6;
  const int quad = lane >> 4, l16 = lane & 15;
  const int we = (wave >> 1) * 64;
  const int wd = (wave & 1) * 64;
  const int NC64 = NPAD >> 6;

  const u16* ap = Vt + (size_t)(ti + we + l16) * NPAD + quad * 8;
  const u16* bp = Kt + (size_t)(tj + wd + l16) * NPAD + quad * 8;

  f32x4 acc[4][4] = {};
  for (int c = s; c < NC64; c += S) {
    size_t nb = (size_t)c << 6;
    s16x8 a0[4], a1[4], b0[4], b1[4];
#pragma unroll
    for (int f = 0; f < 4; ++f) {
      const u16* ar = ap + (size_t)f * 16 * NPAD + nb;
      const u16* br = bp + (size_t)f * 16 * NPAD + nb;
      a0[f] = *(const s16x8*)ar; a1[f] = *(const s16x8*)(ar + 32);
      b0[f] = *(const s16x8*)br; b1[f] = *(const s16x8*)(br + 32);
    }
#pragma unroll
    for (int fr = 0; fr < 4; ++fr)
#pragma unroll
      for (int fc = 0; fc < 4; ++fc)
        acc[fr][fc] = __builtin_amdgcn_mfma_f32_16x16x32_bf16(a0[fr], b0[fc], acc[fr][fc], 0, 0, 0);
#pragma unroll
    for (int fr = 0; fr < 4; ++fr)
#pragma unroll
      for (int fc = 0; fc < 4; ++fc)
        acc[fr][fc] = __builtin_amdgcn_mfma_f32_16x16x32_bf16(a1[fr], b1[fc], acc[fr][fc], 0, 0, 0);
  }

  float* Pp = P + (size_t)s * 65536;
#pragma unroll
  for (int fr = 0; fr < 4; ++fr)
#pragma unroll
    for (int fc = 0; fc < 4; ++fc) {
      int d = tj + wd + fc * 16 + l16;
      int e0 = ti + we + fr * 16 + quad * 4;
      *(f32x4*)&Pp[(size_t)d * 256 + e0] = acc[fr][fc];
    }
}

// ---------------- Stage 4: reduce partials, emit KVtb[e][d] bf16 ----------------
__global__ void kvred_kernel(const float* __restrict__ P, u16* __restrict__ KVtb, int nsp) {
  int d = blockIdx.x;
  int e = threadIdx.x;
  float s = 0.f;
  for (int sp = 0; sp < nsp; ++sp) s += P[(size_t)sp * 65536 + d * 256 + e];
  KVtb[e * 256 + d] = f2bf(s);
}

// ---------------- Stage 5: out[r][e] = (Q@KV)[r][e] / (Q[r].ksum + eps) ----------------
// 64-row Q tile, 256 thr, 4 blk/CU; KVtb (128KB, L2-hot) direct from global.
// Zero barriers in the MFMA loop.
__global__ __launch_bounds__(256, 4)
void out_kernel(const u16* __restrict__ Qb, const u16* __restrict__ KVtb,
                const float* __restrict__ ksum, float* __restrict__ out,
                int N, int NPAD) {
  __shared__ u16 Qs[64][264];
  __shared__ float ks[256];
  __shared__ float nrmp[256];
  __shared__ float nrm[64];
  const int tid = threadIdx.x;
  const int r0 = blockIdx.x * 64;

#pragma unroll
  for (int i = 0; i < 8; ++i) {
    int l = tid + i * 256;
    int row = l >> 5;
    int seg = (l & 31) << 3;
    *(s16x8*)&Qs[row][seg] = *(const s16x8*)&Qb[(size_t)(r0 + row) * 256 + seg];
  }
  ks[tid] = ksum[tid];
  __syncthreads();

  // normalizer: 4 threads per row
  {
    int r = tid & 63, h = tid >> 6;
    float sa = 0.f;
#pragma unroll
    for (int dd = 0; dd < 64; dd += 8) {
      int d = h * 64 + dd;
      s16x8 q = *(const s16x8*)&Qs[r][d];
#pragma unroll
      for (int j = 0; j < 8; ++j) sa += bf2f((u16)q[j]) * ks[d + j];
    }
    nrmp[tid] = sa;
  }
  __syncthreads();
  if (tid < 64)
    nrm[tid] = nrmp[tid] + nrmp[tid + 64] + nrmp[tid + 128] + nrmp[tid + 192] + EPS;
  __syncthreads();

  const int lane = tid & 63, wave = tid >> 6;
  const int quad = lane >> 4, l16 = lane & 15;
  const int eg = wave * 64;   // this wave's 64-e slice

  const u16* ap = KVtb + (size_t)(eg + l16) * 256 + quad * 8;

  f32x4 acc[4][4] = {};
#pragma unroll 2
  for (int c = 0; c < 8; ++c) {
    int kc = c * 32;
    s16x8 a[4], b[4];
#pragma unroll
    for (int f = 0; f < 4; ++f) a[f] = *(const s16x8*)(ap + f * 16 * 256 + kc);
#pragma unroll
    for (int f = 0; f < 4; ++f) b[f] = *(const s16x8*)&Qs[f * 16 + l16][kc + quad * 8];
#pragma unroll
    for (int fr = 0; fr < 4; ++fr)
#pragma unroll
      for (int fc = 0; fc < 4; ++fc)
        acc[fr][fc] = __builtin_amdgcn_mfma_f32_16x16x32_bf16(a[fr], b[fc], acc[fr][fc], 0, 0, 0);
  }

#pragma unroll
  for (int fc = 0; fc < 4; ++fc) {
    int rl = fc * 16 + l16;
    int rg = r0 + rl;
    float inv = 1.0f / nrm[rl];
    if (rg < N) {
#pragma unroll
      for (int fr = 0; fr < 4; ++fr) {
        int e0 = eg + fr * 16 + quad * 4;
        f32x4 o;
        o[0] = acc[fr][fc][0] * inv;
        o[1] = acc[fr][fc][1] * inv;
        o[2] = acc[fr][fc][2] * inv;
        o[3] = acc[fr][fc][3] * inv;
        *(f32x4*)&out[(size_t)rg * 256 + e0] = o;
      }
    }
  }
}

extern "C" void kernel_launch(void* const* d_in, const int* in_sizes, int n_in,
                              void* d_out, int out_size, void* d_ws, size_t ws_size,
                              hipStream_t stream) {
  const float* x  = (const float*)d_in[0];
  const float* Wq = (const float*)d_in[1];
  const float* bq = (const float*)d_in[2];
  const float* Wk = (const float*)d_in[3];
  const float* bk = (const float*)d_in[4];
  const float* Wv = (const float*)d_in[5];
  const float* bv = (const float*)d_in[6];
  float* out = (float*)d_out;

  int N = in_sizes[0] / 256;
  int NPAD = ((N + 127) / 128) * 128;
  int nblkQ = NPAD / 128;
  int nblkO = NPAD / 64;

  size_t szT = (size_t)256 * NPAD * sizeof(u16);
  size_t fixed = 3 * szT + (size_t)65536 * sizeof(u16) + 256 * sizeof(float)
               + 3 * (size_t)65536 * sizeof(u16);
  int S = 256;
  while (S > 32 && fixed + (size_t)S * 65536 * sizeof(float) > ws_size) S >>= 1;

  char* p = (char*)d_ws;
  u16* Kt = (u16*)p; p += szT;
  u16* Vt = (u16*)p; p += szT;
  u16* Qb = (u16*)p; p += szT;
  float* P = (float*)p; p += (size_t)S * 65536 * sizeof(float);
  u16* KVtb = (u16*)p; p += (size_t)65536 * sizeof(u16);
  float* ksum = (float*)p; p += 256 * sizeof(float);
  u16* WqT = (u16*)p; p += (size_t)65536 * sizeof(u16);
  u16* WkT = (u16*)p; p += (size_t)65536 * sizeof(u16);
  u16* WvT = (u16*)p; p += (size_t)65536 * sizeof(u16);

  hipMemsetAsync(ksum, 0, 256 * sizeof(float), stream);
  wtrans_kernel<<<48, 256, 0, stream>>>(Wq, Wk, Wv, WqT, WkT, WvT);
  qkv_kernel<<<nblkQ, 512, 0, stream>>>(x, WqT, WkT, WvT, bq, bk, bv, Qb, Kt, Vt, ksum, N, NPAD);
  kv_kernel<<<S * 4, 256, 0, stream>>>(Kt, Vt, P, NPAD, S);
  kvred_kernel<<<256, 256, 0, stream>>>(P, KVtb, S);
  out_kernel<<<nblkO, 256, 0, stream>>>(Qb, KVtb, ksum, out, N, NPAD);
}

// Round 8
// 440.738 us; speedup vs baseline: 1.1191x; 1.1191x over previous
//
#include <hip/hip_runtime.h>

typedef unsigned short u16;
typedef float f32x4 __attribute__((ext_vector_type(4)));
typedef short s16x8 __attribute__((ext_vector_type(8)));
typedef unsigned short u16x4 __attribute__((ext_vector_type(4)));

#define EPS 1e-6f

static __device__ __forceinline__ u16 f2bf(float f) {
  unsigned u = __float_as_uint(f);
  u += 0x7fffu + ((u >> 16) & 1u);   // RNE
  return (u16)(u >> 16);
}
static __device__ __forceinline__ float bf2f(u16 h) {
  return __uint_as_float(((unsigned)h) << 16);
}

// Async global->LDS DMA, 16B per lane. dst must be the WAVE-UNIFORM base;
// HW adds lane*16. Counts in vmcnt; __syncthreads() drains it.
static __device__ __forceinline__ void gl_lds16(const u16* g, u16* l) {
  __builtin_amdgcn_global_load_lds(
      (const __attribute__((address_space(1))) unsigned int*)g,
      (__attribute__((address_space(3))) unsigned int*)l, 16, 0, 0);
}

// ---------------- Stage 1: weights -> bf16 [col][k], swizzle BAKED ----------------
// Stored k-index = k ^ ((c&3)<<3): DMA-staged linear chunks give conflict-free
// swizzled ds_read_b128 (rule: swizzle both sides or neither).
__global__ void wtrans_kernel(const float* __restrict__ Wq, const float* __restrict__ Wk,
                              const float* __restrict__ Wv,
                              u16* __restrict__ WqT, u16* __restrict__ WkT, u16* __restrict__ WvT) {
  int b = blockIdx.x;
  int mat = b >> 4, cg = b & 15;
  const float* W = mat == 0 ? Wq : (mat == 1 ? Wk : Wv);
  u16* WT = mat == 0 ? WqT : (mat == 1 ? WkT : WvT);
  int t = threadIdx.x;
  int c = cg * 16 + (t & 15);
  int k0 = (t >> 4) * 16;
  for (int i = 0; i < 16; ++i) {
    int k = k0 + i;
    WT[c * 256 + (k ^ ((c & 3) << 3))] = f2bf(W[k * 256 + c]);
  }
}

// ---------------- Stage 2: Q,K,V GEMMs ----------------
// 128-row tile, 256 thr (4 waves = 2 rowg x 2 colg, 64x64 each), 80KB LDS,
// 2 blocks/CU. Weight chunks (128 cols x 32 k = 8KB) staged by global_load_lds
// into a double buffer: STAGE(next) -> ds_read+MFMA(cur) -> barrier. No
// ds_writes, no staging VGPRs. Output swizzles baked for downstream DMA.
__global__ __launch_bounds__(256, 2)
void qkv_kernel(const float* __restrict__ x,
                const u16* __restrict__ WqT, const u16* __restrict__ WkT, const u16* __restrict__ WvT,
                const float* __restrict__ bq, const float* __restrict__ bk, const float* __restrict__ bv,
                u16* __restrict__ Qb, u16* __restrict__ Kt, u16* __restrict__ Vt,
                float* __restrict__ ksum, int N, int NPAD) {
  __shared__ __align__(16) u16 xs[128 * 256];   // x tile, row-swizzled (64 KB)
  __shared__ __align__(16) u16 wst[2][4096];    // weight chunk double buffer (2 x 8 KB)
  const int tid = threadIdx.x;
  const int n0 = blockIdx.x * 128;
  const int lane = tid & 63, wave = tid >> 6;
  const int quad = lane >> 4, l16 = lane & 15;
  const int wr = (wave >> 1) * 64;   // row group
  const int wc = (wave & 1) * 64;    // col group within staged 128

  auto stage = [&](int buf, int it) {
    const int ph = it >> 3, kc = (it & 7) * 32;
    const int mat = ph >> 1, colB = (ph & 1) * 128;
    const u16* WT = mat == 0 ? WqT : (mat == 1 ? WkT : WvT);
    const u16* s0 = WT + (size_t)(colB + (tid >> 2)) * 256 + kc + (tid & 3) * 8;
    u16* d0 = &wst[buf][wave * 512];
    gl_lds16(s0, d0);                      // cols 0..63 of chunk
    gl_lds16(s0 + 64 * 256, d0 + 2048);    // cols 64..127
  };
  stage(0, 0);   // DMA flies while we stage x

  // x tile fp32 -> bf16, row-swizzled ds_writes.
  // 128 rows x 64 float4 = 8192 slots / 256 thr = 32 per thread (R6 bug: was 16).
#pragma unroll
  for (int i = 0; i < 32; ++i) {
    int l = tid + i * 256;
    int row = l >> 6;
    int c4 = (l & 63) << 2;
    int n = n0 + row;
    float4 v = make_float4(0.f, 0.f, 0.f, 0.f);
    if (n < N) v = *(const float4*)(x + (size_t)n * 256 + c4);
    u16x4 pk;
    pk[0] = f2bf(v.x); pk[1] = f2bf(v.y); pk[2] = f2bf(v.z); pk[3] = f2bf(v.w);
    *(u16x4*)&xs[row * 256 + (c4 ^ ((row & 7) << 3))] = pk;
  }
  __syncthreads();   // drains chunk-0 DMA + xs writes

  f32x4 acc[4][4] = {};
  int buf = 0;
  for (int it = 0; it < 48; ++it) {
    const int ph = it >> 3, kc = (it & 7) * 32;
    const int mat = ph >> 1, colBase = (ph & 1) * 128;

    if (it + 1 < 48) stage(buf ^ 1, it + 1);   // full-iteration slack

    s16x8 a[4], b[4];
#pragma unroll
    for (int f = 0; f < 4; ++f) {
      int r = wr + f * 16 + l16;
      a[f] = *(const s16x8*)&xs[r * 256 + ((kc + quad * 8) ^ ((r & 7) << 3))];
    }
#pragma unroll
    for (int f = 0; f < 4; ++f) {
      int cl = wc + f * 16 + l16;
      b[f] = *(const s16x8*)&wst[buf][cl * 32 + ((quad * 8) ^ ((cl & 3) << 3))];
    }
    if (mat == 0) {
      // swapped operands: D row-dim = weight col -> vectorized row-major Q store
#pragma unroll
      for (int fr = 0; fr < 4; ++fr)
#pragma unroll
        for (int fc = 0; fc < 4; ++fc)
          acc[fr][fc] = __builtin_amdgcn_mfma_f32_16x16x32_bf16(b[fc], a[fr], acc[fr][fc], 0, 0, 0);
    } else {
#pragma unroll
      for (int fr = 0; fr < 4; ++fr)
#pragma unroll
        for (int fc = 0; fc < 4; ++fc)
          acc[fr][fc] = __builtin_amdgcn_mfma_f32_16x16x32_bf16(a[fr], b[fc], acc[fr][fc], 0, 0, 0);
    }

    if ((it & 7) == 7) {
      // ---- phase epilogue ----
      if (mat == 0) {
#pragma unroll
        for (int fc = 0; fc < 4; ++fc) {
          int colg4 = colBase + wc + fc * 16 + quad * 4;
          float4 bb = *(const float4*)(bq + colg4);
#pragma unroll
          for (int fr = 0; fr < 4; ++fr) {
            int n = n0 + wr + fr * 16 + l16;
            u16x4 pk;
            pk[0] = f2bf(fmaxf(acc[fr][fc][0] + bb.x, 0.f));
            pk[1] = f2bf(fmaxf(acc[fr][fc][1] + bb.y, 0.f));
            pk[2] = f2bf(fmaxf(acc[fr][fc][2] + bb.z, 0.f));
            pk[3] = f2bf(fmaxf(acc[fr][fc][3] + bb.w, 0.f));
            if (n >= N) { pk[0] = 0; pk[1] = 0; pk[2] = 0; pk[3] = 0; }
            *(u16x4*)&Qb[(size_t)n * 256 + (colg4 ^ ((n & 7) << 3))] = pk;   // baked for out's DMA
          }
        }
      } else {
        u16* T = (mat == 1) ? Kt : Vt;
        const float* bias = (mat == 1) ? bk : bv;
        float ksacc[4] = {0.f, 0.f, 0.f, 0.f};
#pragma unroll
        for (int fc = 0; fc < 4; ++fc) {
          int colg = colBase + wc + fc * 16 + l16;
          float bb = bias[colg];
#pragma unroll
          for (int fr = 0; fr < 4; ++fr) {
            int nb = n0 + wr + fr * 16 + quad * 4;
            u16x4 pk;
#pragma unroll
            for (int j = 0; j < 4; ++j) {
              float v = acc[fr][fc][j] + bb;
              if (mat == 1) v = fmaxf(v, 0.f);
              bool ok = (nb + j < N);
              pk[j] = ok ? f2bf(v) : (u16)0;
              if (mat == 1) ksacc[fc] += ok ? v : 0.f;
            }
            *(u16x4*)&T[(size_t)colg * NPAD + (nb ^ ((colg & 3) << 3))] = pk;  // baked for kv's DMA
          }
        }
        if (mat == 1) {
#pragma unroll
          for (int fc = 0; fc < 4; ++fc) {
            float v = ksacc[fc];
            v += __shfl_xor(v, 16);
            v += __shfl_xor(v, 32);
            if (quad == 0) atomicAdd(&ksum[colBase + wc + fc * 16 + l16], v);
          }
        }
      }
#pragma unroll
      for (int fr = 0; fr < 4; ++fr)
#pragma unroll
        for (int fc = 0; fc < 4; ++fc) acc[fr][fc] = (f32x4){0.f, 0.f, 0.f, 0.f};
    }
    __syncthreads();   // drains next-chunk DMA (+ epilogue stores)
    buf ^= 1;
  }
}

// ---------------- Stage 3: KV^T partials, DMA-staged 2-phase ----------------
// 4 (e,d) quadrants x S n-splits; chunk = 128 rows x 32 n (8KB each for K,V).
__global__ __launch_bounds__(256, 2)
void kv_kernel(const u16* __restrict__ Kt, const u16* __restrict__ Vt,
               float* __restrict__ P, int NPAD, int S) {
  __shared__ __align__(16) u16 As[2][4096];   // Vt rows (e)
  __shared__ __align__(16) u16 Bs[2][4096];   // Kt rows (d)
  const int tid = threadIdx.x;
  const int s = blockIdx.x % S;
  const int g = blockIdx.x / S;
  const int ti = (g >> 1) * 128;
  const int tj = (g & 1) * 128;
  const int lane = tid & 63, wave = tid >> 6;
  const int quad = lane >> 4, l16 = lane & 15;
  const int we = (wave >> 1) * 64;
  const int wd = (wave & 1) * 64;
  const int NCH = NPAD >> 5;

  auto stage = [&](int buf, int c) {
    size_t nb = (size_t)c << 5;
    const u16* sa = Vt + (size_t)(ti + (tid >> 2)) * NPAD + nb + (tid & 3) * 8;
    const u16* sb = Kt + (size_t)(tj + (tid >> 2)) * NPAD + nb + (tid & 3) * 8;
    u16* da = &As[buf][wave * 512];
    u16* db = &Bs[buf][wave * 512];
    gl_lds16(sa, da); gl_lds16(sa + (size_t)64 * NPAD, da + 2048);
    gl_lds16(sb, db); gl_lds16(sb + (size_t)64 * NPAD, db + 2048);
  };

  stage(0, s);
  __syncthreads();

  f32x4 acc[4][4] = {};
  int buf = 0;
  for (int c = s; c < NCH; c += S) {
    if (c + S < NCH) stage(buf ^ 1, c + S);
    s16x8 a[4], b[4];
#pragma unroll
    for (int f = 0; f < 4; ++f) {
      int rl = we + f * 16 + l16;
      a[f] = *(const s16x8*)&As[buf][rl * 32 + ((quad * 8) ^ ((rl & 3) << 3))];
    }
#pragma unroll
    for (int f = 0; f < 4; ++f) {
      int rl = wd + f * 16 + l16;
      b[f] = *(const s16x8*)&Bs[buf][rl * 32 + ((quad * 8) ^ ((rl & 3) << 3))];
    }
#pragma unroll
    for (int fr = 0; fr < 4; ++fr)
#pragma unroll
      for (int fc = 0; fc < 4; ++fc)
        acc[fr][fc] = __builtin_amdgcn_mfma_f32_16x16x32_bf16(a[fr], b[fc], acc[fr][fc], 0, 0, 0);
    __syncthreads();
    buf ^= 1;
  }

  float* Pp = P + (size_t)s * 65536;
#pragma unroll
  for (int fr = 0; fr < 4; ++fr)
#pragma unroll
    for (int fc = 0; fc < 4; ++fc) {
      int d = tj + wd + fc * 16 + l16;
      int e0 = ti + we + fr * 16 + quad * 4;
      *(f32x4*)&Pp[(size_t)d * 256 + e0] = acc[fr][fc];
    }
}

// ---------------- Stage 4: reduce partials -> KVtb[e][d] bf16 (swizzle baked) ----------------
__global__ void kvred_kernel(const float* __restrict__ P, u16* __restrict__ KVtb, int nsp) {
  int d = blockIdx.x;
  int e = threadIdx.x;
  float s = 0.f;
  for (int sp = 0; sp < nsp; ++sp) s += P[(size_t)sp * 65536 + d * 256 + e];
  KVtb[e * 256 + (d ^ ((e & 3) << 3))] = f2bf(s);
}

// ---------------- Stage 5: out = (Q@KV) / (Q.ksum + eps), DMA-staged 2-phase ----------------
__global__ __launch_bounds__(256, 2)
void out_kernel(const u16* __restrict__ Qb, const u16* __restrict__ KVtb,
                const float* __restrict__ ksum, float* __restrict__ out,
                int N, int NPAD) {
  __shared__ __align__(16) u16 Qs[128 * 256];   // 64 KB, baked swizzle (from Qb)
  __shared__ __align__(16) u16 KVs[2][4096];    // KV chunk double buffer
  __shared__ float ks[256];
  __shared__ float nrmp[256];
  __shared__ float nrm[128];
  const int tid = threadIdx.x;
  const int r0 = blockIdx.x * 128;
  const int lane = tid & 63, wave = tid >> 6;
  const int quad = lane >> 4, l16 = lane & 15;
  const int wr2 = (wave >> 1) * 64;   // row group
  const int weg = (wave & 1) * 64;    // e group within 128-half

  auto stageKV = [&](int buf, int it) {
    const int ehn = it >> 3, kcn = (it & 7) * 32;
    const u16* s0 = KVtb + (size_t)(ehn * 128 + (tid >> 2)) * 256 + kcn + (tid & 3) * 8;
    u16* d0 = &KVs[buf][wave * 512];
    gl_lds16(s0, d0);
    gl_lds16(s0 + 64 * 256, d0 + 2048);
  };

  // Q tile via DMA (16 sweeps, linear copy of baked layout)
#pragma unroll
  for (int sweep = 0; sweep < 16; ++sweep) {
    const u16* s0 = Qb + (size_t)r0 * 256 + sweep * 2048 + tid * 8;
    gl_lds16(s0, &Qs[sweep * 2048 + wave * 512]);
  }
  stageKV(0, 0);
  ks[tid] = ksum[tid];
  __syncthreads();

  // normalizer: 2 threads per row
  {
    int r = tid & 127, h = tid >> 7;
    float sa = 0.f;
#pragma unroll
    for (int dd = 0; dd < 128; dd += 8) {
      int d = h * 128 + dd;
      s16x8 q = *(const s16x8*)&Qs[r * 256 + (d ^ ((r & 7) << 3))];
#pragma unroll
      for (int j = 0; j < 8; ++j) sa += bf2f((u16)q[j]) * ks[d + j];
    }
    nrmp[tid] = sa;
  }
  __syncthreads();
  if (tid < 128) nrm[tid] = nrmp[tid] + nrmp[tid + 128] + EPS;
  __syncthreads();

  f32x4 acc[4][4] = {};
  int buf = 0;
  for (int it = 0; it < 16; ++it) {
    const int eh = it >> 3, kc = (it & 7) * 32;
    if (it + 1 < 16) stageKV(buf ^ 1, it + 1);

    s16x8 a[4], b[4];
#pragma unroll
    for (int f = 0; f < 4; ++f) {
      int ec = weg + f * 16 + l16;
      a[f] = *(const s16x8*)&KVs[buf][ec * 32 + ((quad * 8) ^ ((ec & 3) << 3))];
    }
#pragma unroll
    for (int f = 0; f < 4; ++f) {
      int r = wr2 + f * 16 + l16;
      b[f] = *(const s16x8*)&Qs[r * 256 + ((kc + quad * 8) ^ ((r & 7) << 3))];
    }
#pragma unroll
    for (int fr = 0; fr < 4; ++fr)
#pragma unroll
      for (int fc = 0; fc < 4; ++fc)
        acc[fr][fc] = __builtin_amdgcn_mfma_f32_16x16x32_bf16(a[fr], b[fc], acc[fr][fc], 0, 0, 0);

    if ((it & 7) == 7) {
#pragma unroll
      for (int fc = 0; fc < 4; ++fc) {
        int rl = wr2 + fc * 16 + l16;
        int rg = r0 + rl;
        float inv = 1.0f / nrm[rl];
        if (rg < N) {
#pragma unroll
          for (int fr = 0; fr < 4; ++fr) {
            int eg = eh * 128 + weg + fr * 16 + quad * 4;
            f32x4 o;
            o[0] = acc[fr][fc][0] * inv;
            o[1] = acc[fr][fc][1] * inv;
            o[2] = acc[fr][fc][2] * inv;
            o[3] = acc[fr][fc][3] * inv;
            *(f32x4*)&out[(size_t)rg * 256 + eg] = o;
          }
        }
      }
#pragma unroll
      for (int fr = 0; fr < 4; ++fr)
#pragma unroll
        for (int fc = 0; fc < 4; ++fc) acc[fr][fc] = (f32x4){0.f, 0.f, 0.f, 0.f};
    }
    __syncthreads();
    buf ^= 1;
  }
}

extern "C" void kernel_launch(void* const* d_in, const int* in_sizes, int n_in,
                              void* d_out, int out_size, void* d_ws, size_t ws_size,
                              hipStream_t stream) {
  const float* x  = (const float*)d_in[0];
  const float* Wq = (const float*)d_in[1];
  const float* bq = (const float*)d_in[2];
  const float* Wk = (const float*)d_in[3];
  const float* bk = (const float*)d_in[4];
  const float* Wv = (const float*)d_in[5];
  const float* bv = (const float*)d_in[6];
  float* out = (float*)d_out;

  int N = in_sizes[0] / 256;
  int NPAD = ((N + 127) / 128) * 128;
  int nblk = NPAD / 128;

  size_t szT = (size_t)256 * NPAD * sizeof(u16);
  size_t fixed = 3 * szT + (size_t)65536 * sizeof(u16) + 256 * sizeof(float)
               + 3 * (size_t)65536 * sizeof(u16);
  int S = 128;
  while (S > 16 && fixed + (size_t)S * 65536 * sizeof(float) > ws_size) S >>= 1;

  char* p = (char*)d_ws;
  u16* Kt = (u16*)p; p += szT;
  u16* Vt = (u16*)p; p += szT;
  u16* Qb = (u16*)p; p += szT;
  float* P = (float*)p; p += (size_t)S * 65536 * sizeof(float);
  u16* KVtb = (u16*)p; p += (size_t)65536 * sizeof(u16);
  float* ksum = (float*)p; p += 256 * sizeof(float);
  u16* WqT = (u16*)p; p += (size_t)65536 * sizeof(u16);
  u16* WkT = (u16*)p; p += (size_t)65536 * sizeof(u16);
  u16* WvT = (u16*)p; p += (size_t)65536 * sizeof(u16);

  hipMemsetAsync(ksum, 0, 256 * sizeof(float), stream);
  wtrans_kernel<<<48, 256, 0, stream>>>(Wq, Wk, Wv, WqT, WkT, WvT);
  qkv_kernel<<<nblk, 256, 0, stream>>>(x, WqT, WkT, WvT, bq, bk, bv, Qb, Kt, Vt, ksum, N, NPAD);
  kv_kernel<<<S * 4, 256, 0, stream>>>(Kt, Vt, P, NPAD, S);
  kvred_kernel<<<256, 256, 0, stream>>>(P, KVtb, S);
  out_kernel<<<nblk, 256, 0, stream>>>(Qb, KVtb, ksum, out, N, NPAD);
}